// Round 2
// baseline (811.103 us; speedup 1.0000x reference)
//
#include <hip/hip_runtime.h>

// RelMultiHeadAttention (Transformer-XL) on gfx950.
// B=2, S=2048, D=1024, H=16, hd=64.
// R8: amortize per-(b,h) K/R/V reads over 32 q-rows/block (was 16), grid
// 4096->2048 (8 serial slots/CU instead of 16), 2 k-passes of 1024 cols so
// the two LDS strips fit (2 x 32 x 1032 f16 = 129 KB, 1 block/CU). Each
// K/R tile is loaded once and feeds BOTH 16-row groups. x-strip now stores
// head/tail at their logical row, so softmax reads ONE x row (select only
// vs j==i+1). XCD swizzle groups all 64 tiles of a (b,h) on one XCD -> K/R/V
// live in that L2 and are reused 64x. V frags prefetched under exp. psum and
// PV accumulate across passes; fp32 partials reuse the x strip.

typedef float  floatx4 __attribute__((ext_vector_type(4)));
typedef __bf16 bf16x8  __attribute__((ext_vector_type(8)));
typedef _Float16 f16x8 __attribute__((ext_vector_type(8)));
typedef _Float16 f16x4 __attribute__((ext_vector_type(4)));

#define LSTR 40   // proj-GEMM LDS row stride (bf16): conflict-free b128

struct GP {
  const void* A;
  const __bf16* B;
  int lda, ldb, K;
  float* outF;
  __bf16* out1;
  __bf16* out2;
  _Float16* out1h;
  const float* bias;
  const float* rrb;
};

// MODE: 0=Qproj(dual q/qrr) 1=Kproj 2=Vproj(transposed, f16) 3=Rproj 4=OUTproj
template<int MODE, bool AF32>
__global__ void __launch_bounds__(256) gemm_k(GP p) {
  __shared__ __bf16 lA[128 * LSTR];
  __shared__ __bf16 lB[128 * LSTR];
  const int t = threadIdx.x;
  const int wave = t >> 6, lane = t & 63;
  const int m0 = blockIdx.y * 128, n0 = blockIdx.x * 128;
  const int srow = t >> 2, scol = (t & 3) << 3;

  const float*  Af = (const float*)p.A;
  const __bf16* Ab = (const __bf16*)p.A;
  const __bf16* Bb = p.B;

  floatx4 acc[4][4];
#pragma unroll
  for (int i = 0; i < 4; i++)
#pragma unroll
    for (int j = 0; j < 4; j++) acc[i][j] = floatx4{0.f, 0.f, 0.f, 0.f};

  const int lr = lane & 15, lq = lane >> 4;
  const int wr = (wave >> 1) << 6, wc = (wave & 1) << 6;

  for (int kk = 0; kk < p.K; kk += 32) {
#pragma unroll
    for (int h2 = 0; h2 < 2; h2++) {
      int r = srow + (h2 << 6);
      if (AF32) {
        const float* ap = Af + (long)(m0 + r) * p.lda + kk + scol;
        float4 f0 = *(const float4*)ap;
        float4 f1 = *(const float4*)(ap + 4);
        bf16x8 o;
        o[0] = (__bf16)f0.x; o[1] = (__bf16)f0.y; o[2] = (__bf16)f0.z; o[3] = (__bf16)f0.w;
        o[4] = (__bf16)f1.x; o[5] = (__bf16)f1.y; o[6] = (__bf16)f1.z; o[7] = (__bf16)f1.w;
        *(bf16x8*)&lA[r * LSTR + scol] = o;
      } else {
        const __bf16* ap = Ab + (long)(m0 + r) * p.lda + kk + scol;
        *(bf16x8*)&lA[r * LSTR + scol] = *(const bf16x8*)ap;
      }
      const __bf16* bp = Bb + (long)(n0 + r) * p.ldb + kk + scol;
      *(bf16x8*)&lB[r * LSTR + scol] = *(const bf16x8*)bp;
    }
    __syncthreads();
    bf16x8 aF[4], bF[4];
#pragma unroll
    for (int i = 0; i < 4; i++)
      aF[i] = *(bf16x8*)&lA[(wr + i * 16 + lr) * LSTR + (lq << 3)];
#pragma unroll
    for (int i = 0; i < 4; i++)
      bF[i] = *(bf16x8*)&lB[(wc + i * 16 + lr) * LSTR + (lq << 3)];
#pragma unroll
    for (int i = 0; i < 4; i++)
#pragma unroll
      for (int j = 0; j < 4; j++)
        acc[i][j] = __builtin_amdgcn_mfma_f32_16x16x32_bf16(aF[i], bF[j], acc[i][j], 0, 0, 0);
    __syncthreads();
  }

  // C/D layout: col = lane&15, row = (lane>>4)*4 + reg  [measured m89/m91]
#pragma unroll
  for (int i = 0; i < 4; i++) {
#pragma unroll
    for (int j = 0; j < 4; j++) {
      int col = n0 + wc + j * 16 + lr;
#pragma unroll
      for (int g = 0; g < 4; g++) {
        int rl = m0 + wr + i * 16 + (lq << 2) + g;
        float val = acc[i][j][g];
        if constexpr (MODE <= 2) {
          int b = rl >> 11, s = rl & 2047;
          int h = col >> 6, d = col & 63;
          float v = val + p.bias[col];
          if constexpr (MODE == 0) {
            long dst = (((long)(b * 16 + h) * 2048 + s) << 6) + d;
            p.out1[dst] = (__bf16)v;
            p.out2[dst] = (__bf16)(v + p.rrb[col]);
          } else if constexpr (MODE == 1) {
            long dst = (((long)(b * 16 + h) * 2048 + s) << 6) + d;
            p.out1[dst] = (__bf16)v;
          } else {  // V transposed f16: [bh][d][seq]
            long dst = ((((long)(b * 16 + h)) << 6) + d) * 2048 + s;
            p.out1h[dst] = (_Float16)v;
          }
        } else if constexpr (MODE == 3) {
          int h = col >> 6, d = col & 63;
          long dst = (((long)h * 2048 + rl) << 6) + d;
          p.out1[dst] = (__bf16)val;
        } else {  // MODE 4
          p.outF[(long)rl * 1024 + col] = val + p.bias[col];
        }
      }
    }
  }
}

__global__ void __launch_bounds__(256) cb_k(const __bf16* kb, const float* rwb, float* cb) {
  long id = (long)blockIdx.x * 256 + threadIdx.x;  // 32*2048
  int z = (int)(id >> 11);
  int j = (int)(id & 2047);
  int h = z & 15;
  const __bf16* kp = kb + (((long)z * 2048 + j) << 6);
  float s = 0.f;
#pragma unroll
  for (int c = 0; c < 8; c++) {
    bf16x8 kv = *(const bf16x8*)(kp + c * 8);
#pragma unroll
    for (int e = 0; e < 8; e++) s += rwb[h * 64 + c * 8 + e] * (float)kv[e];
  }
  cb[id] = s * 0.125f;
}

__global__ void __launch_bounds__(256) tr_cvt(const float* src, __bf16* dst) {
  __shared__ float tile[64][65];
  int bx = blockIdx.x, by = blockIdx.y;
  int tx = threadIdx.x & 63, ty = threadIdx.x >> 6;
#pragma unroll
  for (int r = ty; r < 64; r += 4)
    tile[r][tx] = src[(long)(by * 64 + r) * 1024 + bx * 64 + tx];
  __syncthreads();
#pragma unroll
  for (int r = ty; r < 64; r += 4)
    dst[(long)(bx * 64 + r) * 1024 + by * 64 + tx] = (__bf16)tile[tx][r];
}

// -------- fused scores + rel-shift + softmax + PV: 32 rows, 2 k-passes -----
#define QSTR2 1032                        // strip row stride (f16 elems)
#define SM_STRIP (32 * QSTR2 * 2)         // 66048 B per strip
#define FUSED_SMEM (2 * SM_STRIP)         // 132096 B -> 1 block/CU

__global__ void __launch_bounds__(1024) fused_k(const __bf16* __restrict__ qb,
                                                const __bf16* __restrict__ qrr,
                                                const __bf16* __restrict__ kb,
                                                const _Float16* __restrict__ vt,
                                                const __bf16* __restrict__ rb,
                                                const float* __restrict__ cb,
                                                __bf16* __restrict__ attnb) {
  extern __shared__ char smem[];
  _Float16* qkS = (_Float16*)smem;            // scores f16 [32][QSTR2]
  _Float16* xS  = (_Float16*)(smem + SM_STRIP);  // shifted x f16 [32][QSTR2]

  const int t = threadIdx.x;
  const int w = t >> 6, lane = t & 63, lr = lane & 15, lq = lane >> 4;
  // XCD swizzle: 2048 blocks, 8 XCDs -> all 64 tiles of a (b,h) on one XCD.
  const int obid = blockIdx.x;
  const int bid = ((obid & 7) << 8) | (obid >> 3);
  const int z  = bid >> 6;
  const int i0 = (bid & 63) << 5;
  const int b = z >> 4, h = z & 15;
  const bool early = (i0 <= 1023);
  const int astart = early ? i0 + 1 : i0;    // 32 MFMA x-rows [astart, astart+32)

  // B-frags: q rows i0+rg*16+lr, qrr rows astart+rg*16+lr
  bf16x8 bq[2][2], br[2][2];
#pragma unroll
  for (int rg = 0; rg < 2; rg++) {
    const __bf16* qp = qb + (((long)z * 2048 + i0 + rg * 16 + lr) << 6) + lq * 8;
    bq[rg][0] = *(const bf16x8*)qp; bq[rg][1] = *(const bf16x8*)(qp + 32);
    const __bf16* rp = qrr + (((long)z * 2048 + astart + rg * 16 + lr) << 6) + lq * 8;
    br[rg][0] = *(const bf16x8*)rp; br[rg][1] = *(const bf16x8*)(rp + 32);
  }

  const __bf16* kbz = kb + (((long)z * 2048) << 6);
  const __bf16* rbh = rb + (((long)h * 2048) << 6);
  const float* cbz = cb + (long)z * 2048;
  const _Float16* vtz = vt + (((long)z) << 6) * 2048;
  const int w8 = w & 7, rgp = w >> 3;   // PV: 8 waves per 16-row group

  floatx4 oacc[4];
#pragma unroll
  for (int s = 0; s < 4; s++) oacc[s] = floatx4{0.f, 0.f, 0.f, 0.f};
  float psum0 = 0.f, psum1 = 0.f;

  for (int kp = 0; kp < 2; kp++) {
    const int J0 = kp << 10;

    // qk MFMA (+cb fold): 64 j-tiles, wave does 4, each feeds BOTH row-groups.
    // D: row(lq*4+g)=key-local, col(lr)=q-row.
#pragma unroll
    for (int s = 0; s < 4; s++) {
      const int jb = (w + (s << 4)) << 4;     // local col base
      const __bf16* ap = kbz + ((long)(J0 + jb + lr) << 6) + lq * 8;
      bf16x8 a0 = *(const bf16x8*)ap, a1 = *(const bf16x8*)(ap + 32);
      floatx4 cbv = *(const floatx4*)(cbz + J0 + jb + lq * 4);
      floatx4 c0{0.f, 0.f, 0.f, 0.f}, c1{0.f, 0.f, 0.f, 0.f};
      c0 = __builtin_amdgcn_mfma_f32_16x16x32_bf16(a0, bq[0][0], c0, 0, 0, 0);
      c0 = __builtin_amdgcn_mfma_f32_16x16x32_bf16(a1, bq[0][1], c0, 0, 0, 0);
      c1 = __builtin_amdgcn_mfma_f32_16x16x32_bf16(a0, bq[1][0], c1, 0, 0, 0);
      c1 = __builtin_amdgcn_mfma_f32_16x16x32_bf16(a1, bq[1][1], c1, 0, 0, 0);
      f16x4 s0v, s1v;
#pragma unroll
      for (int g = 0; g < 4; g++) {
        s0v[g] = (_Float16)(c0[g] * 0.125f + cbv[g]);
        s1v[g] = (_Float16)(c1[g] * 0.125f + cbv[g]);
      }
      *(f16x4*)&qkS[lr * QSTR2 + jb + lq * 4] = s0v;
      *(f16x4*)&qkS[(16 + lr) * QSTR2 + jb + lq * 4] = s1v;
    }

    // x MFMA: m-window for j in [J0,J0+1024), a in [astart, astart+32):
    // 67 tiles from mbase; each tile feeds both row-groups. Scatter with
    // shift pre-applied: j=(m+a+1)&2047, tail(sum>=2048)->row a, head->a-1.
    const int s0m = (J0 - astart - 32) & 2047;
    const int mbase = s0m & ~15;
    for (int s = 0; s < 5; s++) {
      const int mt = w + (s << 4);
      if (mt >= 67) break;
      const int m0 = (mbase + (mt << 4)) & 2047;
      const __bf16* rp2 = rbh + ((long)(m0 + lr) << 6) + lq * 8;
      bf16x8 r0 = *(const bf16x8*)rp2, r1 = *(const bf16x8*)(rp2 + 32);
      floatx4 x0{0.f, 0.f, 0.f, 0.f}, x1{0.f, 0.f, 0.f, 0.f};
      x0 = __builtin_amdgcn_mfma_f32_16x16x32_bf16(r0, br[0][0], x0, 0, 0, 0);
      x0 = __builtin_amdgcn_mfma_f32_16x16x32_bf16(r1, br[0][1], x0, 0, 0, 0);
      x1 = __builtin_amdgcn_mfma_f32_16x16x32_bf16(r0, br[1][0], x1, 0, 0, 0);
      x1 = __builtin_amdgcn_mfma_f32_16x16x32_bf16(r1, br[1][1], x1, 0, 0, 0);
#pragma unroll
      for (int rg = 0; rg < 2; rg++) {
        const int a = astart + (rg << 4) + lr;
        const floatx4 ax = rg ? x1 : x0;
#pragma unroll
        for (int g = 0; g < 4; g++) {
          const int m = m0 + (lq << 2) + g;
          const int sum = m + a + 1;
          const int j = sum & 2047;
          const int ri = (sum >= 2048) ? (a - i0) : (a - i0 - 1);
          const int jl = j - J0;
          if ((unsigned)ri < 32u && (unsigned)jl < 1024u)
            xS[ri * QSTR2 + jl] = (_Float16)(ax[g] * 0.125f);
        }
      }
    }

    // boundary GEMV (the 33rd x-row): early a=i0 tail (pass 0, row 0, cols
    // [0,i0]); late a=i0+32 head (pass 1, row 31, cols [i0+33,2048)).
    if (early ? (kp == 0) : (kp == 1)) {
      const int glen = early ? i0 + 1 : 2015 - i0;
      if (t < glen) {
        const int ga   = early ? i0 : i0 + 32;
        const int grow = early ? 0 : 31;
        const int gj   = early ? t : (i0 + 33 + t);
        const int gm   = early ? (2047 - i0 + t) : t;
        const __bf16* qrp = qrr + (((long)z * 2048 + ga) << 6);
        const __bf16* rrp = rbh + ((long)gm << 6);
        float sdot = 0.f;
#pragma unroll
        for (int c8 = 0; c8 < 8; c8++) {
          bf16x8 qv = *(const bf16x8*)(qrp + c8 * 8);
          bf16x8 rv = *(const bf16x8*)(rrp + c8 * 8);
#pragma unroll
          for (int e = 0; e < 8; e++) sdot += (float)qv[e] * (float)rv[e];
        }
        xS[grow * QSTR2 + (gj - J0)] = (_Float16)(sdot * 0.125f);
      }
    }
    __syncthreads();   // A: both strips complete for this pass

    // V B-frag prefetch for ks 0,1 — latency hidden under exp
    f16x8 vA[8];
#pragma unroll
    for (int ks = 0; ks < 2; ks++)
#pragma unroll
      for (int sub = 0; sub < 4; sub++)
        vA[ks * 4 + sub] = *(const f16x8*)(vtz + (long)(sub * 16 + lr) * 2048 +
                                           J0 + w8 * 128 + ks * 32 + lq * 8);

    // exp: wave handles rows w and w+16. One x-row read; select only j==i+1.
#pragma unroll
    for (int half = 0; half < 2; half++) {
      const int r = w + (half << 4);
      const int iA = i0 + r;
      _Float16* qrow = qkS + r * QSTR2;
      const _Float16* xrow = xS + r * QSTR2;
      float ps = 0.f;
#pragma unroll
      for (int ii = 0; ii < 2; ii++) {
        const int j0l = ii * 512 + lane * 8;
        f16x8 hv = *(const f16x8*)(qrow + j0l);
        f16x8 xv = *(const f16x8*)(xrow + j0l);
        f16x8 pr;
#pragma unroll
        for (int e = 0; e < 8; e++) {
          const int jg = J0 + j0l + e;
          const float xf = (jg == iA + 1) ? 0.f : (float)xv[e];
          const float ev = __expf((float)hv[e] + xf);
          ps += ev;
          pr[e] = (_Float16)ev;
        }
        *(f16x8*)(qrow + j0l) = pr;
      }
      if (half) psum1 += ps; else psum0 += ps;
    }
    __syncthreads();   // B: p~ complete, xS reads done

    // PV: 8 waves per row-group, 128 keys each per pass; accumulate oacc.
    f16x8 vB[8];
#pragma unroll
    for (int ks = 0; ks < 2; ks++)
#pragma unroll
      for (int sub = 0; sub < 4; sub++)
        vB[ks * 4 + sub] = *(const f16x8*)(vtz + (long)(sub * 16 + lr) * 2048 +
                                           J0 + w8 * 128 + (ks + 2) * 32 + lq * 8);
#pragma unroll
    for (int ks = 0; ks < 4; ks++) {
      f16x8 af = *(const f16x8*)(qkS + (rgp * 16 + lr) * QSTR2 + w8 * 128 + ks * 32 + lq * 8);
      const f16x8* vsel = (ks < 2) ? &vA[ks * 4] : &vB[(ks - 2) * 4];
#pragma unroll
      for (int sub = 0; sub < 4; sub++)
        oacc[sub] = __builtin_amdgcn_mfma_f32_16x16x32_f16(af, vsel[sub], oacc[sub], 0, 0, 0);
    }
    if (kp == 0) __syncthreads();   // C: strip reads done before pass-1 P12
  }

  // fp32 partials [w8][32][64] into the xS region (dead since barrier B)
  {
    float* sPart = (float*)xS;
#pragma unroll
    for (int sub = 0; sub < 4; sub++)
#pragma unroll
      for (int g = 0; g < 4; g++)
        sPart[w8 * 2048 + (rgp * 16 + (lq << 2) + g) * 64 + sub * 16 + lr] = oacc[sub][g];
  }
#pragma unroll
  for (int o = 1; o < 64; o <<= 1) {
    psum0 += __shfl_xor(psum0, o, 64);
    psum1 += __shfl_xor(psum1, o, 64);
  }
  const float inv0 = 1.0f / psum0, inv1 = 1.0f / psum1;
  __syncthreads();   // D: partials complete

  // reduce 8 PV waves; normalize rows w and w+16 by this wave's sums
  {
    const float* sPart = (const float*)xS;
#pragma unroll
    for (int half = 0; half < 2; half++) {
      const int rl = w + (half << 4);
      float accO = 0.f;
#pragma unroll
      for (int w8i = 0; w8i < 8; w8i++) accO += sPart[w8i * 2048 + rl * 64 + lane];
      attnb[((long)b * 2048 + i0 + rl) * 1024 + h * 64 + lane] =
          (__bf16)(accO * (half ? inv1 : inv0));
    }
  }
}

extern "C" void kernel_launch(void* const* d_in, const int* in_sizes, int n_in,
                              void* d_out, int out_size, void* d_ws, size_t ws_size,
                              hipStream_t stream) {
  (void)in_sizes; (void)n_in; (void)out_size; (void)ws_size;
  const float* inputs_kv = (const float*)d_in[0];
  const float* inputs_q  = (const float*)d_in[1];
  const float* pos_embed = (const float*)d_in[2];
  const float* Wq_w = (const float*)d_in[3];
  const float* Wq_b = (const float*)d_in[4];
  const float* Wk_w = (const float*)d_in[5];
  const float* Wk_b = (const float*)d_in[6];
  const float* Wv_w = (const float*)d_in[7];
  const float* Wv_b = (const float*)d_in[8];
  const float* Wr_w = (const float*)d_in[9];
  const float* rwb  = (const float*)d_in[10];
  const float* rrb  = (const float*)d_in[11];
  const float* Wo_w = (const float*)d_in[12];
  const float* Wo_b = (const float*)d_in[13];

  char* ws = (char*)d_ws;
  const long MB = 1 << 20;
  __bf16* Wtq = (__bf16*)(ws + 0 * MB);
  __bf16* Wtk = (__bf16*)(ws + 2 * MB);
  __bf16* Wtv = (__bf16*)(ws + 4 * MB);
  __bf16* Wtr = (__bf16*)(ws + 6 * MB);
  __bf16* Wto = (__bf16*)(ws + 8 * MB);
  __bf16* qb  = (__bf16*)(ws + 10 * MB);
  __bf16* qrr = (__bf16*)(ws + 18 * MB);
  __bf16* kb  = (__bf16*)(ws + 26 * MB);
  _Float16* vt = (_Float16*)(ws + 34 * MB);
  __bf16* rb  = (__bf16*)(ws + 42 * MB);
  float*  cb  = (float*)(ws + 46 * MB);               // 256 KB
  __bf16* attnb = (__bf16*)(ws + 47 * MB);            // 8 MB bf16 attention out

  dim3 blk(256);

  tr_cvt<<<dim3(16, 16), blk, 0, stream>>>(Wq_w, Wtq);
  tr_cvt<<<dim3(16, 16), blk, 0, stream>>>(Wk_w, Wtk);
  tr_cvt<<<dim3(16, 16), blk, 0, stream>>>(Wv_w, Wtv);
  tr_cvt<<<dim3(16, 16), blk, 0, stream>>>(Wr_w, Wtr);
  tr_cvt<<<dim3(16, 16), blk, 0, stream>>>(Wo_w, Wto);

  GP p{};
  p.lda = 1024; p.ldb = 1024; p.K = 1024;

  p.A = inputs_q; p.B = Wtq; p.out1 = qb; p.out2 = qrr; p.bias = Wq_b; p.rrb = rrb;
  gemm_k<0, true><<<dim3(8, 32, 1), blk, 0, stream>>>(p);
  p.A = inputs_kv; p.B = Wtk; p.out1 = kb; p.out2 = nullptr; p.bias = Wk_b;
  gemm_k<1, true><<<dim3(8, 32, 1), blk, 0, stream>>>(p);
  p.A = inputs_kv; p.B = Wtv; p.out1h = vt; p.bias = Wv_b;
  gemm_k<2, true><<<dim3(8, 32, 1), blk, 0, stream>>>(p);
  p.A = pos_embed; p.B = Wtr; p.out1 = rb; p.bias = nullptr;
  gemm_k<3, true><<<dim3(8, 16, 1), blk, 0, stream>>>(p);

  cb_k<<<dim3(256), blk, 0, stream>>>(kb, rwb, cb);

  hipFuncSetAttribute((const void*)fused_k,
                      hipFuncAttributeMaxDynamicSharedMemorySize, FUSED_SMEM);
  fused_k<<<dim3(2048), dim3(1024), FUSED_SMEM, stream>>>(qb, qrr, kb, vt, rb, cb, attnb);

  // Output projection: d_out = attn(bf16) @ Wo + bo
  GP o{};
  o.A = attnb; o.B = Wto; o.lda = 1024; o.ldb = 1024; o.K = 1024;
  o.bias = Wo_b; o.outF = (float*)d_out;
  gemm_k<4, false><<<dim3(8, 32, 1), blk, 0, stream>>>(o);
}

// Round 3
// 544.959 us; speedup vs baseline: 1.4884x; 1.4884x over previous
//
#include <hip/hip_runtime.h>

// RelMultiHeadAttention (Transformer-XL) on gfx950.
// B=2, S=2048, D=1024, H=16, hd=64.
// R9: concurrency-structure rewrite. fused_k -> 256-thread (4-wave) blocks,
// 32 q-rows, 16 j-passes of width 128; LDS 17.4 KB/block -> 4 independent
// barrier groups per CU (R6-R8 were one 16-wave convoy; ~70% exposed
// latency). VGPR capped at 128 (launch_bounds(256,4)) to kill R8's scratch
// spill (630 MB WRITE_SIZE). Q/K/V/R projections merged into ONE 896-block
// launch (job table) instead of 4 serialized ~1-block/CU launches.

typedef float  floatx4 __attribute__((ext_vector_type(4)));
typedef __bf16 bf16x8  __attribute__((ext_vector_type(8)));
typedef _Float16 f16x8 __attribute__((ext_vector_type(8)));
typedef _Float16 f16x4 __attribute__((ext_vector_type(4)));

#define LSTR 40   // proj-GEMM LDS row stride (bf16): conflict-free b128

struct GP {
  const void* A;
  const __bf16* B;
  int lda, ldb, K;
  float* outF;
  __bf16* out1;
  const float* bias;
};

// Output projection only (attn bf16 @ Wo + bo -> f32)
__global__ void __launch_bounds__(256) gemm_o(GP p) {
  __shared__ __bf16 lA[128 * LSTR];
  __shared__ __bf16 lB[128 * LSTR];
  const int t = threadIdx.x;
  const int wave = t >> 6, lane = t & 63;
  const int m0 = blockIdx.y * 128, n0 = blockIdx.x * 128;
  const int srow = t >> 2, scol = (t & 3) << 3;
  const __bf16* Ab = (const __bf16*)p.A;
  const __bf16* Bb = p.B;

  floatx4 acc[4][4];
#pragma unroll
  for (int i = 0; i < 4; i++)
#pragma unroll
    for (int j = 0; j < 4; j++) acc[i][j] = floatx4{0.f, 0.f, 0.f, 0.f};

  const int lr = lane & 15, lq = lane >> 4;
  const int wr = (wave >> 1) << 6, wc = (wave & 1) << 6;

  for (int kk = 0; kk < p.K; kk += 32) {
#pragma unroll
    for (int h2 = 0; h2 < 2; h2++) {
      int r = srow + (h2 << 6);
      const __bf16* ap = Ab + (long)(m0 + r) * p.lda + kk + scol;
      *(bf16x8*)&lA[r * LSTR + scol] = *(const bf16x8*)ap;
      const __bf16* bp = Bb + (long)(n0 + r) * p.ldb + kk + scol;
      *(bf16x8*)&lB[r * LSTR + scol] = *(const bf16x8*)bp;
    }
    __syncthreads();
    bf16x8 aF[4], bF[4];
#pragma unroll
    for (int i = 0; i < 4; i++)
      aF[i] = *(bf16x8*)&lA[(wr + i * 16 + lr) * LSTR + (lq << 3)];
#pragma unroll
    for (int i = 0; i < 4; i++)
      bF[i] = *(bf16x8*)&lB[(wc + i * 16 + lr) * LSTR + (lq << 3)];
#pragma unroll
    for (int i = 0; i < 4; i++)
#pragma unroll
      for (int j = 0; j < 4; j++)
        acc[i][j] = __builtin_amdgcn_mfma_f32_16x16x32_bf16(aF[i], bF[j], acc[i][j], 0, 0, 0);
    __syncthreads();
  }
#pragma unroll
  for (int i = 0; i < 4; i++)
#pragma unroll
    for (int j = 0; j < 4; j++) {
      int col = n0 + wc + j * 16 + lr;
#pragma unroll
      for (int g = 0; g < 4; g++) {
        int rl = m0 + wr + i * 16 + (lq << 2) + g;
        p.outF[(long)rl * 1024 + col] = acc[i][j][g] + p.bias[col];
      }
    }
}

// ---- merged Q/K/V/R projection: one launch, job table ----------------------
struct QPAll {
  const float *qin, *kvin, *pos;
  const __bf16 *Wtq, *Wtk, *Wtv, *Wtr;
  const float *bq, *bk, *bv, *rrb;
  __bf16 *qb, *qrr, *kb, *rb;
  _Float16 *vt;
};

__global__ void __launch_bounds__(256, 3) qkvr_k(QPAll p) {
  __shared__ __bf16 lA[128 * LSTR];
  __shared__ __bf16 lB[128 * LSTR];
  const int jb = blockIdx.x;
  const int job = (jb >= 768) ? 3 : (jb >> 8);
  const int local = jb - ((job == 3) ? 768 : (job << 8));
  const int m0 = (local >> 3) * 128, n0 = (local & 7) * 128;

  const float* A; const __bf16* B; const float* bias;
  if (job == 0)      { A = p.qin;  B = p.Wtq; bias = p.bq; }
  else if (job == 1) { A = p.kvin; B = p.Wtk; bias = p.bk; }
  else if (job == 2) { A = p.kvin; B = p.Wtv; bias = p.bv; }
  else               { A = p.pos;  B = p.Wtr; bias = nullptr; }

  const int t = threadIdx.x;
  const int wave = t >> 6, lane = t & 63;
  const int srow = t >> 2, scol = (t & 3) << 3;

  floatx4 acc[4][4];
#pragma unroll
  for (int i = 0; i < 4; i++)
#pragma unroll
    for (int j = 0; j < 4; j++) acc[i][j] = floatx4{0.f, 0.f, 0.f, 0.f};

  const int lr = lane & 15, lq = lane >> 4;
  const int wr = (wave >> 1) << 6, wc = (wave & 1) << 6;

  for (int kk = 0; kk < 1024; kk += 32) {
#pragma unroll
    for (int h2 = 0; h2 < 2; h2++) {
      int r = srow + (h2 << 6);
      const float* ap = A + (long)(m0 + r) * 1024 + kk + scol;
      float4 f0 = *(const float4*)ap;
      float4 f1 = *(const float4*)(ap + 4);
      bf16x8 o;
      o[0] = (__bf16)f0.x; o[1] = (__bf16)f0.y; o[2] = (__bf16)f0.z; o[3] = (__bf16)f0.w;
      o[4] = (__bf16)f1.x; o[5] = (__bf16)f1.y; o[6] = (__bf16)f1.z; o[7] = (__bf16)f1.w;
      *(bf16x8*)&lA[r * LSTR + scol] = o;
      const __bf16* bp = B + (long)(n0 + r) * 1024 + kk + scol;
      *(bf16x8*)&lB[r * LSTR + scol] = *(const bf16x8*)bp;
    }
    __syncthreads();
    bf16x8 aF[4], bF[4];
#pragma unroll
    for (int i = 0; i < 4; i++)
      aF[i] = *(bf16x8*)&lA[(wr + i * 16 + lr) * LSTR + (lq << 3)];
#pragma unroll
    for (int i = 0; i < 4; i++)
      bF[i] = *(bf16x8*)&lB[(wc + i * 16 + lr) * LSTR + (lq << 3)];
#pragma unroll
    for (int i = 0; i < 4; i++)
#pragma unroll
      for (int j = 0; j < 4; j++)
        acc[i][j] = __builtin_amdgcn_mfma_f32_16x16x32_bf16(aF[i], bF[j], acc[i][j], 0, 0, 0);
    __syncthreads();
  }

  // epilogue per job; C/D: col=lane&15, row=(lane>>4)*4+reg
#pragma unroll
  for (int i = 0; i < 4; i++)
#pragma unroll
    for (int j = 0; j < 4; j++) {
      int col = n0 + wc + j * 16 + lr;
#pragma unroll
      for (int g = 0; g < 4; g++) {
        int rl = m0 + wr + i * 16 + (lq << 2) + g;
        float val = acc[i][j][g];
        int hh = col >> 6, d = col & 63;
        if (job == 3) {
          long dst = (((long)hh * 2048 + rl) << 6) + d;
          p.rb[dst] = (__bf16)val;
        } else {
          int bb = rl >> 11, s = rl & 2047;
          float v = val + bias[col];
          if (job == 0) {
            long dst = (((long)(bb * 16 + hh) * 2048 + s) << 6) + d;
            p.qb[dst] = (__bf16)v;
            p.qrr[dst] = (__bf16)(v + p.rrb[col]);
          } else if (job == 1) {
            long dst = (((long)(bb * 16 + hh) * 2048 + s) << 6) + d;
            p.kb[dst] = (__bf16)v;
          } else {
            long dst = ((((long)(bb * 16 + hh)) << 6) + d) * 2048 + s;
            p.vt[dst] = (_Float16)v;
          }
        }
      }
    }
}

__global__ void __launch_bounds__(256) cb_k(const __bf16* kb, const float* rwb, float* cb) {
  long id = (long)blockIdx.x * 256 + threadIdx.x;  // 32*2048
  int z = (int)(id >> 11);
  int j = (int)(id & 2047);
  int h = z & 15;
  const __bf16* kp = kb + (((long)z * 2048 + j) << 6);
  float s = 0.f;
#pragma unroll
  for (int c = 0; c < 8; c++) {
    bf16x8 kv = *(const bf16x8*)(kp + c * 8);
#pragma unroll
    for (int e = 0; e < 8; e++) s += rwb[h * 64 + c * 8 + e] * (float)kv[e];
  }
  cb[id] = s * 0.125f;
}

__global__ void __launch_bounds__(256) tr_cvt(const float* src, __bf16* dst) {
  __shared__ float tile[64][65];
  int bx = blockIdx.x, by = blockIdx.y;
  int tx = threadIdx.x & 63, ty = threadIdx.x >> 6;
#pragma unroll
  for (int r = ty; r < 64; r += 4)
    tile[r][tx] = src[(long)(by * 64 + r) * 1024 + bx * 64 + tx];
  __syncthreads();
#pragma unroll
  for (int r = ty; r < 64; r += 4)
    dst[(long)(bx * 64 + r) * 1024 + by * 64 + tx] = (__bf16)tile[tx][r];
}

// -------- fused scores + rel-shift + softmax + PV: 4-wave blocks -----------
// 32 q-rows/block, 16 j-passes of width 128. Strips [32][QSTR3] f16 (qk, x).
// Per pass: qk+x MFMA + boundary GEMV -> barrier -> exp (in-place) -> barrier
// -> PV (split 2 rg x 2 k-slices over 4 waves) -> barrier. fp32 partials
// overlay the strips after the last pass.
#define QW 128
#define QSTR3 136                         // row stride f16; 2-way bank (free)
#define SM_ONE (32 * QSTR3 * 2)           // 8704 B per strip
#define FUSED_SMEM (2 * SM_ONE)           // 17408 B -> 4+ blocks/CU

__global__ void __launch_bounds__(256, 4) fused_k(const __bf16* __restrict__ qb,
                                                  const __bf16* __restrict__ qrr,
                                                  const __bf16* __restrict__ kb,
                                                  const _Float16* __restrict__ vt,
                                                  const __bf16* __restrict__ rb,
                                                  const float* __restrict__ cb,
                                                  __bf16* __restrict__ attnb) {
  extern __shared__ char smem[];
  _Float16* qkS = (_Float16*)smem;              // [32][QSTR3]
  _Float16* xS  = (_Float16*)(smem + SM_ONE);   // [32][QSTR3]
  __shared__ float sInv[32];

  const int t = threadIdx.x;
  const int w = t >> 6, lane = t & 63, lr = lane & 15, lq = lane >> 4;
  // XCD swizzle: all 64 tiles of a (b,h) on one XCD.
  const int obid = blockIdx.x;
  const int bid = ((obid & 7) << 8) | (obid >> 3);
  const int z  = bid >> 6;
  const int i0 = (bid & 63) << 5;
  const int b = z >> 4, h = z & 15;
  const bool early = (i0 <= 1023);
  const int astart = early ? i0 + 1 : i0;   // 32 MFMA x-rows [astart, astart+32)

  // B-frags: q rows i0+rg*16+lr, qrr rows astart+rg*16+lr
  bf16x8 fq[2][2], fr[2][2];
#pragma unroll
  for (int rg = 0; rg < 2; rg++) {
    const __bf16* qp = qb + (((long)z * 2048 + i0 + rg * 16 + lr) << 6) + lq * 8;
    fq[rg][0] = *(const bf16x8*)qp; fq[rg][1] = *(const bf16x8*)(qp + 32);
    const __bf16* rp = qrr + (((long)z * 2048 + astart + rg * 16 + lr) << 6) + lq * 8;
    fr[rg][0] = *(const bf16x8*)rp; fr[rg][1] = *(const bf16x8*)(rp + 32);
  }

  const __bf16* kbz = kb + (((long)z * 2048) << 6);
  const __bf16* rbh = rb + (((long)h * 2048) << 6);
  const float* cbz = cb + (long)z * 2048;
  const _Float16* vtz = vt + (((long)z) << 6) * 2048;

  const int erow = w * 8 + (lane >> 3);     // exp row for this lane
  const int ecol = (lane & 7) * 16;         // exp col base within pass
  const int rg = w >> 1, sl = w & 1;        // PV role: row-group, k-slice

  floatx4 oacc[4];
#pragma unroll
  for (int s = 0; s < 4; s++) oacc[s] = floatx4{0.f, 0.f, 0.f, 0.f};
  float psum = 0.f;

  for (int kp = 0; kp < 16; kp++) {
    const int J0 = kp << 7;

    // qk MFMA (+cb fold): 8 j-tiles, wave does 2. D: row=key-local, col=q-row.
#pragma unroll
    for (int s = 0; s < 2; s++) {
      const int jt = ((w << 1) + s) << 4;     // 0..112
      const __bf16* ap = kbz + ((long)(J0 + jt + lr) << 6) + lq * 8;
      bf16x8 a0 = *(const bf16x8*)ap, a1 = *(const bf16x8*)(ap + 32);
      floatx4 cbv = *(const floatx4*)(cbz + J0 + jt + lq * 4);
      floatx4 c0{0.f, 0.f, 0.f, 0.f}, c1{0.f, 0.f, 0.f, 0.f};
      c0 = __builtin_amdgcn_mfma_f32_16x16x32_bf16(a0, fq[0][0], c0, 0, 0, 0);
      c0 = __builtin_amdgcn_mfma_f32_16x16x32_bf16(a1, fq[0][1], c0, 0, 0, 0);
      c1 = __builtin_amdgcn_mfma_f32_16x16x32_bf16(a0, fq[1][0], c1, 0, 0, 0);
      c1 = __builtin_amdgcn_mfma_f32_16x16x32_bf16(a1, fq[1][1], c1, 0, 0, 0);
      f16x4 s0v, s1v;
#pragma unroll
      for (int g = 0; g < 4; g++) {
        s0v[g] = (_Float16)(c0[g] * 0.125f + cbv[g]);
        s1v[g] = (_Float16)(c1[g] * 0.125f + cbv[g]);
      }
      *(f16x4*)&qkS[lr * QSTR3 + jt + lq * 4] = s0v;
      *(f16x4*)&qkS[(16 + lr) * QSTR3 + jt + lq * 4] = s1v;
    }

    // x MFMA: m-window = (j - a - 1) mod 2048 over j in pass, a in 32 rows ->
    // 159 consecutive values -> <=11 tiles. Scatter with shift pre-applied.
    const int mb = ((J0 - astart - 32) & 2047) & ~15;
    for (int s = 0; s < 3; s++) {
      const int mt = w + (s << 2);
      if (mt >= 11) break;
      const int m0 = (mb + (mt << 4)) & 2047;
      const __bf16* rp2 = rbh + ((long)(m0 + lr) << 6) + lq * 8;
      bf16x8 r0 = *(const bf16x8*)rp2, r1 = *(const bf16x8*)(rp2 + 32);
      floatx4 x0{0.f, 0.f, 0.f, 0.f}, x1{0.f, 0.f, 0.f, 0.f};
      x0 = __builtin_amdgcn_mfma_f32_16x16x32_bf16(r0, fr[0][0], x0, 0, 0, 0);
      x0 = __builtin_amdgcn_mfma_f32_16x16x32_bf16(r1, fr[0][1], x0, 0, 0, 0);
      x1 = __builtin_amdgcn_mfma_f32_16x16x32_bf16(r0, fr[1][0], x1, 0, 0, 0);
      x1 = __builtin_amdgcn_mfma_f32_16x16x32_bf16(r1, fr[1][1], x1, 0, 0, 0);
#pragma unroll
      for (int rg2 = 0; rg2 < 2; rg2++) {
        const int a = astart + (rg2 << 4) + lr;
        const floatx4 ax = rg2 ? x1 : x0;
#pragma unroll
        for (int g = 0; g < 4; g++) {
          const int m = m0 + (lq << 2) + g;
          const int sum = m + a + 1;
          const int j = sum & 2047;
          const int ri = (sum >= 2048) ? (a - i0) : (a - i0 - 1);
          const int jl = j - J0;
          if ((unsigned)ri < 32u && (unsigned)jl < (unsigned)QW)
            xS[ri * QSTR3 + jl] = (_Float16)(ax[g] * 0.125f);
        }
      }
    }

    // boundary GEMV (the 33rd x-row), cols of this pass only.
    if (t < QW) {
      const int j = J0 + t;
      const bool act = early ? (j <= i0) : (j >= i0 + 33);
      if (act) {
        const int ga = early ? i0 : i0 + 32;
        const int grow = early ? 0 : 31;
        const int m = early ? (j + 2047 - i0) : (j - i0 - 33);
        const __bf16* qrp = qrr + (((long)z * 2048 + ga) << 6);
        const __bf16* rrp = rbh + ((long)m << 6);
        float sdot = 0.f;
#pragma unroll
        for (int c8 = 0; c8 < 8; c8++) {
          bf16x8 qv = *(const bf16x8*)(qrp + c8 * 8);
          bf16x8 rv = *(const bf16x8*)(rrp + c8 * 8);
#pragma unroll
          for (int e = 0; e < 8; e++) sdot += (float)qv[e] * (float)rv[e];
        }
        xS[grow * QSTR3 + t] = (_Float16)(sdot * 0.125f);
      }
    }
    __syncthreads();   // A: strips complete

    // exp in place: row erow, 16 cols from ecol; select zero at j==i+1.
    {
      const int iA = i0 + erow;
      _Float16* qrow = qkS + erow * QSTR3 + ecol;
      const _Float16* xrow = xS + erow * QSTR3 + ecol;
      f16x8 h0 = *(const f16x8*)qrow, h1 = *(const f16x8*)(qrow + 8);
      f16x8 v0 = *(const f16x8*)xrow, v1 = *(const f16x8*)(xrow + 8);
      f16x8 p0, p1;
#pragma unroll
      for (int e = 0; e < 8; e++) {
        const int jg = J0 + ecol + e;
        float xf = (jg == iA + 1) ? 0.f : (float)v0[e];
        float ev = __expf((float)h0[e] + xf);
        psum += ev; p0[e] = (_Float16)ev;
        const int jg1 = jg + 8;
        float xf1 = (jg1 == iA + 1) ? 0.f : (float)v1[e];
        float ev1 = __expf((float)h1[e] + xf1);
        psum += ev1; p1[e] = (_Float16)ev1;
      }
      *(f16x8*)qrow = p0;
      *(f16x8*)(qrow + 8) = p1;
    }
    __syncthreads();   // B: p~ complete

    // PV: wave (rg, sl) contracts keys [J0+sl*64, +64) for rows rg*16..+16
#pragma unroll
    for (int ch = 0; ch < 2; ch++) {
      const int kk = sl * 64 + ch * 32;
      f16x8 af = *(const f16x8*)(qkS + (rg * 16 + lr) * QSTR3 + kk + lq * 8);
#pragma unroll
      for (int sub = 0; sub < 4; sub++) {
        f16x8 bfv = *(const f16x8*)(vtz + (long)(sub * 16 + lr) * 2048 + J0 + kk + lq * 8);
        oacc[sub] = __builtin_amdgcn_mfma_f32_16x16x32_f16(af, bfv, oacc[sub], 0, 0, 0);
      }
    }
    __syncthreads();   // C: strip reads done before next pass overwrites
  }

  // fp32 partials overlay the strips (dead after barrier C of last pass)
  {
    float* sPart = (float*)smem;   // [2*rg+sl][16][64]
#pragma unroll
    for (int sub = 0; sub < 4; sub++)
#pragma unroll
      for (int g = 0; g < 4; g++)
        sPart[((rg << 1) + sl) * 1024 + ((lq << 2) + g) * 64 + sub * 16 + lr] = oacc[sub][g];
  }
  // row sums: reduce 8 col-lanes of each row
#pragma unroll
  for (int o = 1; o < 8; o <<= 1) psum += __shfl_xor(psum, o, 64);
  if ((lane & 7) == 0) sInv[erow] = 1.0f / psum;
  __syncthreads();   // D: partials + sInv complete

  // final: 256 threads x 8 outputs (32 rows x 64 d)
  {
    const float* sPart = (const float*)smem;
    const int r = t >> 3, d0 = (t & 7) << 3;
    const int rg2 = r >> 4, rl = r & 15;
    const float inv = sInv[r];
    bf16x8 ov;
#pragma unroll
    for (int e = 0; e < 8; e++) {
      float acc = sPart[(rg2 << 1) * 1024 + rl * 64 + d0 + e] +
                  sPart[((rg2 << 1) + 1) * 1024 + rl * 64 + d0 + e];
      ov[e] = (__bf16)(acc * inv);
    }
    *(bf16x8*)&attnb[((long)b * 2048 + i0 + r) * 1024 + h * 64 + d0] = ov;
  }
}

extern "C" void kernel_launch(void* const* d_in, const int* in_sizes, int n_in,
                              void* d_out, int out_size, void* d_ws, size_t ws_size,
                              hipStream_t stream) {
  (void)in_sizes; (void)n_in; (void)out_size; (void)ws_size;
  const float* inputs_kv = (const float*)d_in[0];
  const float* inputs_q  = (const float*)d_in[1];
  const float* pos_embed = (const float*)d_in[2];
  const float* Wq_w = (const float*)d_in[3];
  const float* Wq_b = (const float*)d_in[4];
  const float* Wk_w = (const float*)d_in[5];
  const float* Wk_b = (const float*)d_in[6];
  const float* Wv_w = (const float*)d_in[7];
  const float* Wv_b = (const float*)d_in[8];
  const float* Wr_w = (const float*)d_in[9];
  const float* rwb  = (const float*)d_in[10];
  const float* rrb  = (const float*)d_in[11];
  const float* Wo_w = (const float*)d_in[12];
  const float* Wo_b = (const float*)d_in[13];

  char* ws = (char*)d_ws;
  const long MB = 1 << 20;
  __bf16* Wtq = (__bf16*)(ws + 0 * MB);
  __bf16* Wtk = (__bf16*)(ws + 2 * MB);
  __bf16* Wtv = (__bf16*)(ws + 4 * MB);
  __bf16* Wtr = (__bf16*)(ws + 6 * MB);
  __bf16* Wto = (__bf16*)(ws + 8 * MB);
  __bf16* qb  = (__bf16*)(ws + 10 * MB);
  __bf16* qrr = (__bf16*)(ws + 18 * MB);
  __bf16* kb  = (__bf16*)(ws + 26 * MB);
  _Float16* vt = (_Float16*)(ws + 34 * MB);
  __bf16* rb  = (__bf16*)(ws + 42 * MB);
  float*  cb  = (float*)(ws + 46 * MB);               // 256 KB
  __bf16* attnb = (__bf16*)(ws + 47 * MB);            // 8 MB bf16 attention out

  dim3 blk(256);

  tr_cvt<<<dim3(16, 16), blk, 0, stream>>>(Wq_w, Wtq);
  tr_cvt<<<dim3(16, 16), blk, 0, stream>>>(Wk_w, Wtk);
  tr_cvt<<<dim3(16, 16), blk, 0, stream>>>(Wv_w, Wtv);
  tr_cvt<<<dim3(16, 16), blk, 0, stream>>>(Wr_w, Wtr);
  tr_cvt<<<dim3(16, 16), blk, 0, stream>>>(Wo_w, Wto);

  QPAll q{};
  q.qin = inputs_q; q.kvin = inputs_kv; q.pos = pos_embed;
  q.Wtq = Wtq; q.Wtk = Wtk; q.Wtv = Wtv; q.Wtr = Wtr;
  q.bq = Wq_b; q.bk = Wk_b; q.bv = Wv_b; q.rrb = rrb;
  q.qb = qb; q.qrr = qrr; q.kb = kb; q.rb = rb; q.vt = vt;
  qkvr_k<<<dim3(896), blk, 0, stream>>>(q);

  cb_k<<<dim3(256), blk, 0, stream>>>(kb, rwb, cb);

  fused_k<<<dim3(2048), dim3(256), FUSED_SMEM, stream>>>(qb, qrr, kb, vt, rb, cb, attnb);

  // Output projection: d_out = attn(bf16) @ Wo + bo
  GP o{};
  o.A = attnb; o.B = Wto; o.lda = 1024; o.ldb = 1024; o.K = 1024;
  o.bias = Wo_b; o.outF = (float*)d_out;
  gemm_o<<<dim3(8, 32), blk, 0, stream>>>(o);
}

// Round 4
// 521.433 us; speedup vs baseline: 1.5555x; 1.0451x over previous
//
#include <hip/hip_runtime.h>

// RelMultiHeadAttention (Transformer-XL) on gfx950.
// B=2, S=2048, D=1024, H=16, hd=64.
// R10: R9 (4-wave blocks, 16 j-passes, 8 blocks/CU) + boundary-GEMV hoisted
// out of the pass loop. R9 recomputed a 64-length dot per column PER PASS
// with scattered (64-line) global loads -> ~55-110us of TA serialization
// per CU. Now: one coalesced pass over the boundary row into xB[1024] LDS
// (8 lanes/column, consecutive columns = consecutive 128B rows, shfl_xor
// reduce), and phase A just copies the pass's slice xB -> xS (LDS->LDS).
// exp/PV numerics unchanged. Also: 5 tr_cvt launches merged into one.

typedef float  floatx4 __attribute__((ext_vector_type(4)));
typedef __bf16 bf16x8  __attribute__((ext_vector_type(8)));
typedef _Float16 f16x8 __attribute__((ext_vector_type(8)));
typedef _Float16 f16x4 __attribute__((ext_vector_type(4)));

#define LSTR 40   // proj-GEMM LDS row stride (bf16): conflict-free b128

struct GP {
  const void* A;
  const __bf16* B;
  int lda, ldb, K;
  float* outF;
  __bf16* out1;
  const float* bias;
};

// Output projection only (attn bf16 @ Wo + bo -> f32)
__global__ void __launch_bounds__(256) gemm_o(GP p) {
  __shared__ __bf16 lA[128 * LSTR];
  __shared__ __bf16 lB[128 * LSTR];
  const int t = threadIdx.x;
  const int wave = t >> 6, lane = t & 63;
  const int m0 = blockIdx.y * 128, n0 = blockIdx.x * 128;
  const int srow = t >> 2, scol = (t & 3) << 3;
  const __bf16* Ab = (const __bf16*)p.A;
  const __bf16* Bb = p.B;

  floatx4 acc[4][4];
#pragma unroll
  for (int i = 0; i < 4; i++)
#pragma unroll
    for (int j = 0; j < 4; j++) acc[i][j] = floatx4{0.f, 0.f, 0.f, 0.f};

  const int lr = lane & 15, lq = lane >> 4;
  const int wr = (wave >> 1) << 6, wc = (wave & 1) << 6;

  for (int kk = 0; kk < p.K; kk += 32) {
#pragma unroll
    for (int h2 = 0; h2 < 2; h2++) {
      int r = srow + (h2 << 6);
      const __bf16* ap = Ab + (long)(m0 + r) * p.lda + kk + scol;
      *(bf16x8*)&lA[r * LSTR + scol] = *(const bf16x8*)ap;
      const __bf16* bp = Bb + (long)(n0 + r) * p.ldb + kk + scol;
      *(bf16x8*)&lB[r * LSTR + scol] = *(const bf16x8*)bp;
    }
    __syncthreads();
    bf16x8 aF[4], bF[4];
#pragma unroll
    for (int i = 0; i < 4; i++)
      aF[i] = *(bf16x8*)&lA[(wr + i * 16 + lr) * LSTR + (lq << 3)];
#pragma unroll
    for (int i = 0; i < 4; i++)
      bF[i] = *(bf16x8*)&lB[(wc + i * 16 + lr) * LSTR + (lq << 3)];
#pragma unroll
    for (int i = 0; i < 4; i++)
#pragma unroll
      for (int j = 0; j < 4; j++)
        acc[i][j] = __builtin_amdgcn_mfma_f32_16x16x32_bf16(aF[i], bF[j], acc[i][j], 0, 0, 0);
    __syncthreads();
  }
#pragma unroll
  for (int i = 0; i < 4; i++)
#pragma unroll
    for (int j = 0; j < 4; j++) {
      int col = n0 + wc + j * 16 + lr;
#pragma unroll
      for (int g = 0; g < 4; g++) {
        int rl = m0 + wr + i * 16 + (lq << 2) + g;
        p.outF[(long)rl * 1024 + col] = acc[i][j][g] + p.bias[col];
      }
    }
}

// ---- merged Q/K/V/R projection: one launch, job table ----------------------
struct QPAll {
  const float *qin, *kvin, *pos;
  const __bf16 *Wtq, *Wtk, *Wtv, *Wtr;
  const float *bq, *bk, *bv, *rrb;
  __bf16 *qb, *qrr, *kb, *rb;
  _Float16 *vt;
};

__global__ void __launch_bounds__(256, 3) qkvr_k(QPAll p) {
  __shared__ __bf16 lA[128 * LSTR];
  __shared__ __bf16 lB[128 * LSTR];
  const int jb = blockIdx.x;
  const int job = (jb >= 768) ? 3 : (jb >> 8);
  const int local = jb - ((job == 3) ? 768 : (job << 8));
  const int m0 = (local >> 3) * 128, n0 = (local & 7) * 128;

  const float* A; const __bf16* B; const float* bias;
  if (job == 0)      { A = p.qin;  B = p.Wtq; bias = p.bq; }
  else if (job == 1) { A = p.kvin; B = p.Wtk; bias = p.bk; }
  else if (job == 2) { A = p.kvin; B = p.Wtv; bias = p.bv; }
  else               { A = p.pos;  B = p.Wtr; bias = nullptr; }

  const int t = threadIdx.x;
  const int wave = t >> 6, lane = t & 63;
  const int srow = t >> 2, scol = (t & 3) << 3;

  floatx4 acc[4][4];
#pragma unroll
  for (int i = 0; i < 4; i++)
#pragma unroll
    for (int j = 0; j < 4; j++) acc[i][j] = floatx4{0.f, 0.f, 0.f, 0.f};

  const int lr = lane & 15, lq = lane >> 4;
  const int wr = (wave >> 1) << 6, wc = (wave & 1) << 6;

  for (int kk = 0; kk < 1024; kk += 32) {
#pragma unroll
    for (int h2 = 0; h2 < 2; h2++) {
      int r = srow + (h2 << 6);
      const float* ap = A + (long)(m0 + r) * 1024 + kk + scol;
      float4 f0 = *(const float4*)ap;
      float4 f1 = *(const float4*)(ap + 4);
      bf16x8 o;
      o[0] = (__bf16)f0.x; o[1] = (__bf16)f0.y; o[2] = (__bf16)f0.z; o[3] = (__bf16)f0.w;
      o[4] = (__bf16)f1.x; o[5] = (__bf16)f1.y; o[6] = (__bf16)f1.z; o[7] = (__bf16)f1.w;
      *(bf16x8*)&lA[r * LSTR + scol] = o;
      const __bf16* bp = B + (long)(n0 + r) * 1024 + kk + scol;
      *(bf16x8*)&lB[r * LSTR + scol] = *(const bf16x8*)bp;
    }
    __syncthreads();
    bf16x8 aF[4], bF[4];
#pragma unroll
    for (int i = 0; i < 4; i++)
      aF[i] = *(bf16x8*)&lA[(wr + i * 16 + lr) * LSTR + (lq << 3)];
#pragma unroll
    for (int i = 0; i < 4; i++)
      bF[i] = *(bf16x8*)&lB[(wc + i * 16 + lr) * LSTR + (lq << 3)];
#pragma unroll
    for (int i = 0; i < 4; i++)
#pragma unroll
      for (int j = 0; j < 4; j++)
        acc[i][j] = __builtin_amdgcn_mfma_f32_16x16x32_bf16(aF[i], bF[j], acc[i][j], 0, 0, 0);
    __syncthreads();
  }

  // epilogue per job; C/D: col=lane&15, row=(lane>>4)*4+reg
#pragma unroll
  for (int i = 0; i < 4; i++)
#pragma unroll
    for (int j = 0; j < 4; j++) {
      int col = n0 + wc + j * 16 + lr;
#pragma unroll
      for (int g = 0; g < 4; g++) {
        int rl = m0 + wr + i * 16 + (lq << 2) + g;
        float val = acc[i][j][g];
        int hh = col >> 6, d = col & 63;
        if (job == 3) {
          long dst = (((long)hh * 2048 + rl) << 6) + d;
          p.rb[dst] = (__bf16)val;
        } else {
          int bb = rl >> 11, s = rl & 2047;
          float v = val + bias[col];
          if (job == 0) {
            long dst = (((long)(bb * 16 + hh) * 2048 + s) << 6) + d;
            p.qb[dst] = (__bf16)v;
            p.qrr[dst] = (__bf16)(v + p.rrb[col]);
          } else if (job == 1) {
            long dst = (((long)(bb * 16 + hh) * 2048 + s) << 6) + d;
            p.kb[dst] = (__bf16)v;
          } else {
            long dst = ((((long)(bb * 16 + hh)) << 6) + d) * 2048 + s;
            p.vt[dst] = (_Float16)v;
          }
        }
      }
    }
}

__global__ void __launch_bounds__(256) cb_k(const __bf16* kb, const float* rwb, float* cb) {
  long id = (long)blockIdx.x * 256 + threadIdx.x;  // 32*2048
  int z = (int)(id >> 11);
  int j = (int)(id & 2047);
  int h = z & 15;
  const __bf16* kp = kb + (((long)z * 2048 + j) << 6);
  float s = 0.f;
#pragma unroll
  for (int c = 0; c < 8; c++) {
    bf16x8 kv = *(const bf16x8*)(kp + c * 8);
#pragma unroll
    for (int e = 0; e < 8; e++) s += rwb[h * 64 + c * 8 + e] * (float)kv[e];
  }
  cb[id] = s * 0.125f;
}

// All five weight transposes in one launch: 5 x 256 tiles.
struct TRP { const float* src[5]; __bf16* dst[5]; };
__global__ void __launch_bounds__(256) tr_cvt_all(TRP p) {
  __shared__ float tile[64][65];
  const int id = blockIdx.x;
  const int which = id >> 8;
  const int local = id & 255;
  const int bx = local & 15, by = local >> 4;
  const float* src = p.src[which];
  __bf16* dst = p.dst[which];
  int tx = threadIdx.x & 63, ty = threadIdx.x >> 6;
#pragma unroll
  for (int r = ty; r < 64; r += 4)
    tile[r][tx] = src[(long)(by * 64 + r) * 1024 + bx * 64 + tx];
  __syncthreads();
#pragma unroll
  for (int r = ty; r < 64; r += 4)
    dst[(long)(bx * 64 + r) * 1024 + by * 64 + tx] = (__bf16)tile[tx][r];
}

// -------- fused scores + rel-shift + softmax + PV: 4-wave blocks -----------
// 32 q-rows/block, 16 j-passes of width 128. Strips [32][QSTR3] f16 (qk, x)
// + xB[1024] f16 (precomputed boundary row). Per pass: qk+x MFMA + boundary
// slice copy -> barrier -> exp -> barrier -> PV -> barrier.
#define QW 128
#define QSTR3 136                         // row stride f16; 2-way bank (free)
#define SM_ONE (32 * QSTR3 * 2)           // 8704 B per strip
#define FUSED_SMEM (2 * SM_ONE + 2048)    // 19456 B -> 8 blocks/CU

__global__ void __launch_bounds__(256, 4) fused_k(const __bf16* __restrict__ qb,
                                                  const __bf16* __restrict__ qrr,
                                                  const __bf16* __restrict__ kb,
                                                  const _Float16* __restrict__ vt,
                                                  const __bf16* __restrict__ rb,
                                                  const float* __restrict__ cb,
                                                  __bf16* __restrict__ attnb) {
  extern __shared__ char smem[];
  _Float16* qkS = (_Float16*)smem;              // [32][QSTR3]
  _Float16* xS  = (_Float16*)(smem + SM_ONE);   // [32][QSTR3]
  _Float16* xB  = (_Float16*)(smem + 2 * SM_ONE);  // [1024] boundary row
  __shared__ float sInv[32];

  const int t = threadIdx.x;
  const int w = t >> 6, lane = t & 63, lr = lane & 15, lq = lane >> 4;
  // XCD swizzle: all 64 tiles of a (b,h) on one XCD.
  const int obid = blockIdx.x;
  const int bid = ((obid & 7) << 8) | (obid >> 3);
  const int z  = bid >> 6;
  const int i0 = (bid & 63) << 5;
  const int b = z >> 4, h = z & 15;
  const bool early = (i0 <= 1023);
  const int astart = early ? i0 + 1 : i0;   // 32 MFMA x-rows [astart, astart+32)
  const int grow = early ? 0 : 31;          // boundary strip row
  const int c0   = early ? 0 : i0 + 33;     // boundary col range start

  // B-frags: q rows i0+rg*16+lr, qrr rows astart+rg*16+lr
  bf16x8 fq[2][2], fr[2][2];
#pragma unroll
  for (int rg = 0; rg < 2; rg++) {
    const __bf16* qp = qb + (((long)z * 2048 + i0 + rg * 16 + lr) << 6) + lq * 8;
    fq[rg][0] = *(const bf16x8*)qp; fq[rg][1] = *(const bf16x8*)(qp + 32);
    const __bf16* rp = qrr + (((long)z * 2048 + astart + rg * 16 + lr) << 6) + lq * 8;
    fr[rg][0] = *(const bf16x8*)rp; fr[rg][1] = *(const bf16x8*)(rp + 32);
  }

  const __bf16* kbz = kb + (((long)z * 2048) << 6);
  const __bf16* rbh = rb + (((long)h * 2048) << 6);
  const float* cbz = cb + (long)z * 2048;
  const _Float16* vtz = vt + (((long)z) << 6) * 2048;

  // ---- boundary row, once per block, coalesced: 8 lanes per column --------
  // early: ga=i0 (tail), cols [0,i0], m=2047-i0+c; late: ga=i0+32 (head),
  // cols [i0+33,2047], m=c. Consecutive columns = consecutive R rows.
  {
    const int ga    = early ? i0 : i0 + 32;
    const int m0g   = early ? (2047 - i0) : 0;
    int ncols = early ? (i0 + 1) : (2015 - i0);
    if (ncols < 0) ncols = 0;
    const int dl = (t & 7) << 3;          // 8 d's per lane
    bf16x8 qv = *(const bf16x8*)(qrr + (((long)z * 2048 + ga) << 6) + dl);
    for (int c = t >> 3; c < ncols; c += 32) {
      bf16x8 rv = *(const bf16x8*)(rbh + ((long)(m0g + c) << 6) + dl);
      float s = 0.f;
#pragma unroll
      for (int e = 0; e < 8; e++) s += (float)qv[e] * (float)rv[e];
      s += __shfl_xor(s, 1, 64);
      s += __shfl_xor(s, 2, 64);
      s += __shfl_xor(s, 4, 64);
      if ((t & 7) == 0) xB[c] = (_Float16)(s * 0.125f);
    }
  }
  __syncthreads();   // xB visible to all waves

  const int erow = w * 8 + (lane >> 3);     // exp row for this lane
  const int ecol = (lane & 7) * 16;         // exp col base within pass
  const int rg = w >> 1, sl = w & 1;        // PV role: row-group, k-slice

  floatx4 oacc[4];
#pragma unroll
  for (int s = 0; s < 4; s++) oacc[s] = floatx4{0.f, 0.f, 0.f, 0.f};
  float psum = 0.f;

  for (int kp = 0; kp < 16; kp++) {
    const int J0 = kp << 7;

    // qk MFMA (+cb fold): 8 j-tiles, wave does 2. D: row=key-local, col=q-row.
#pragma unroll
    for (int s = 0; s < 2; s++) {
      const int jt = ((w << 1) + s) << 4;     // 0..112
      const __bf16* ap = kbz + ((long)(J0 + jt + lr) << 6) + lq * 8;
      bf16x8 a0 = *(const bf16x8*)ap, a1 = *(const bf16x8*)(ap + 32);
      floatx4 cbv = *(const floatx4*)(cbz + J0 + jt + lq * 4);
      floatx4 c0v{0.f, 0.f, 0.f, 0.f}, c1v{0.f, 0.f, 0.f, 0.f};
      c0v = __builtin_amdgcn_mfma_f32_16x16x32_bf16(a0, fq[0][0], c0v, 0, 0, 0);
      c0v = __builtin_amdgcn_mfma_f32_16x16x32_bf16(a1, fq[0][1], c0v, 0, 0, 0);
      c1v = __builtin_amdgcn_mfma_f32_16x16x32_bf16(a0, fq[1][0], c1v, 0, 0, 0);
      c1v = __builtin_amdgcn_mfma_f32_16x16x32_bf16(a1, fq[1][1], c1v, 0, 0, 0);
      f16x4 s0v, s1v;
#pragma unroll
      for (int g = 0; g < 4; g++) {
        s0v[g] = (_Float16)(c0v[g] * 0.125f + cbv[g]);
        s1v[g] = (_Float16)(c1v[g] * 0.125f + cbv[g]);
      }
      *(f16x4*)&qkS[lr * QSTR3 + jt + lq * 4] = s0v;
      *(f16x4*)&qkS[(16 + lr) * QSTR3 + jt + lq * 4] = s1v;
    }

    // x MFMA: m-window = (j - a - 1) mod 2048 over j in pass, a in 32 rows ->
    // 159 consecutive values -> <=11 tiles. Scatter with shift pre-applied.
    const int mb = ((J0 - astart - 32) & 2047) & ~15;
    for (int s = 0; s < 3; s++) {
      const int mt = w + (s << 2);
      if (mt >= 11) break;
      const int m0 = (mb + (mt << 4)) & 2047;
      const __bf16* rp2 = rbh + ((long)(m0 + lr) << 6) + lq * 8;
      bf16x8 r0 = *(const bf16x8*)rp2, r1 = *(const bf16x8*)(rp2 + 32);
      floatx4 x0{0.f, 0.f, 0.f, 0.f}, x1{0.f, 0.f, 0.f, 0.f};
      x0 = __builtin_amdgcn_mfma_f32_16x16x32_bf16(r0, fr[0][0], x0, 0, 0, 0);
      x0 = __builtin_amdgcn_mfma_f32_16x16x32_bf16(r1, fr[0][1], x0, 0, 0, 0);
      x1 = __builtin_amdgcn_mfma_f32_16x16x32_bf16(r0, fr[1][0], x1, 0, 0, 0);
      x1 = __builtin_amdgcn_mfma_f32_16x16x32_bf16(r1, fr[1][1], x1, 0, 0, 0);
#pragma unroll
      for (int rg2 = 0; rg2 < 2; rg2++) {
        const int a = astart + (rg2 << 4) + lr;
        const floatx4 ax = rg2 ? x1 : x0;
#pragma unroll
        for (int g = 0; g < 4; g++) {
          const int m = m0 + (lq << 2) + g;
          const int sum = m + a + 1;
          const int j = sum & 2047;
          const int ri = (sum >= 2048) ? (a - i0) : (a - i0 - 1);
          const int jl = j - J0;
          if ((unsigned)ri < 32u && (unsigned)jl < (unsigned)QW)
            xS[ri * QSTR3 + jl] = (_Float16)(ax[g] * 0.125f);
        }
      }
    }

    // boundary slice: copy this pass's cols from xB (LDS->LDS, replaces GEMV)
    if (t < QW) {
      const int j = J0 + t;
      const bool act = early ? (j <= i0) : (j >= c0);
      if (act) xS[grow * QSTR3 + t] = xB[j - c0];
    }
    __syncthreads();   // A: strips complete

    // exp in place: row erow, 16 cols from ecol; select zero at j==i+1.
    {
      const int iA = i0 + erow;
      _Float16* qrow = qkS + erow * QSTR3 + ecol;
      const _Float16* xrow = xS + erow * QSTR3 + ecol;
      f16x8 h0 = *(const f16x8*)qrow, h1 = *(const f16x8*)(qrow + 8);
      f16x8 v0 = *(const f16x8*)xrow, v1 = *(const f16x8*)(xrow + 8);
      f16x8 p0, p1;
#pragma unroll
      for (int e = 0; e < 8; e++) {
        const int jg = J0 + ecol + e;
        float xf = (jg == iA + 1) ? 0.f : (float)v0[e];
        float ev = __expf((float)h0[e] + xf);
        psum += ev; p0[e] = (_Float16)ev;
        const int jg1 = jg + 8;
        float xf1 = (jg1 == iA + 1) ? 0.f : (float)v1[e];
        float ev1 = __expf((float)h1[e] + xf1);
        psum += ev1; p1[e] = (_Float16)ev1;
      }
      *(f16x8*)qrow = p0;
      *(f16x8*)(qrow + 8) = p1;
    }
    __syncthreads();   // B: p~ complete

    // PV: wave (rg, sl) contracts keys [J0+sl*64, +64) for rows rg*16..+16
#pragma unroll
    for (int ch = 0; ch < 2; ch++) {
      const int kk = sl * 64 + ch * 32;
      f16x8 af = *(const f16x8*)(qkS + (rg * 16 + lr) * QSTR3 + kk + lq * 8);
#pragma unroll
      for (int sub = 0; sub < 4; sub++) {
        f16x8 bfv = *(const f16x8*)(vtz + (long)(sub * 16 + lr) * 2048 + J0 + kk + lq * 8);
        oacc[sub] = __builtin_amdgcn_mfma_f32_16x16x32_f16(af, bfv, oacc[sub], 0, 0, 0);
      }
    }
    __syncthreads();   // C: strip reads done before next pass overwrites
  }

  // fp32 partials overlay the strips (dead after barrier C of last pass)
  {
    float* sPart = (float*)smem;   // [2*rg+sl][16][64]
#pragma unroll
    for (int sub = 0; sub < 4; sub++)
#pragma unroll
      for (int g = 0; g < 4; g++)
        sPart[((rg << 1) + sl) * 1024 + ((lq << 2) + g) * 64 + sub * 16 + lr] = oacc[sub][g];
  }
  // row sums: reduce 8 col-lanes of each row
#pragma unroll
  for (int o = 1; o < 8; o <<= 1) psum += __shfl_xor(psum, o, 64);
  if ((lane & 7) == 0) sInv[erow] = 1.0f / psum;
  __syncthreads();   // D: partials + sInv complete

  // final: 256 threads x 8 outputs (32 rows x 64 d)
  {
    const float* sPart = (const float*)smem;
    const int r = t >> 3, d0 = (t & 7) << 3;
    const int rg2 = r >> 4, rl = r & 15;
    const float inv = sInv[r];
    bf16x8 ov;
#pragma unroll
    for (int e = 0; e < 8; e++) {
      float acc = sPart[(rg2 << 1) * 1024 + rl * 64 + d0 + e] +
                  sPart[((rg2 << 1) + 1) * 1024 + rl * 64 + d0 + e];
      ov[e] = (__bf16)(acc * inv);
    }
    *(bf16x8*)&attnb[((long)b * 2048 + i0 + r) * 1024 + h * 64 + d0] = ov;
  }
}

extern "C" void kernel_launch(void* const* d_in, const int* in_sizes, int n_in,
                              void* d_out, int out_size, void* d_ws, size_t ws_size,
                              hipStream_t stream) {
  (void)in_sizes; (void)n_in; (void)out_size; (void)ws_size;
  const float* inputs_kv = (const float*)d_in[0];
  const float* inputs_q  = (const float*)d_in[1];
  const float* pos_embed = (const float*)d_in[2];
  const float* Wq_w = (const float*)d_in[3];
  const float* Wq_b = (const float*)d_in[4];
  const float* Wk_w = (const float*)d_in[5];
  const float* Wk_b = (const float*)d_in[6];
  const float* Wv_w = (const float*)d_in[7];
  const float* Wv_b = (const float*)d_in[8];
  const float* Wr_w = (const float*)d_in[9];
  const float* rwb  = (const float*)d_in[10];
  const float* rrb  = (const float*)d_in[11];
  const float* Wo_w = (const float*)d_in[12];
  const float* Wo_b = (const float*)d_in[13];

  char* ws = (char*)d_ws;
  const long MB = 1 << 20;
  __bf16* Wtq = (__bf16*)(ws + 0 * MB);
  __bf16* Wtk = (__bf16*)(ws + 2 * MB);
  __bf16* Wtv = (__bf16*)(ws + 4 * MB);
  __bf16* Wtr = (__bf16*)(ws + 6 * MB);
  __bf16* Wto = (__bf16*)(ws + 8 * MB);
  __bf16* qb  = (__bf16*)(ws + 10 * MB);
  __bf16* qrr = (__bf16*)(ws + 18 * MB);
  __bf16* kb  = (__bf16*)(ws + 26 * MB);
  _Float16* vt = (_Float16*)(ws + 34 * MB);
  __bf16* rb  = (__bf16*)(ws + 42 * MB);
  float*  cb  = (float*)(ws + 46 * MB);               // 256 KB
  __bf16* attnb = (__bf16*)(ws + 47 * MB);            // 8 MB bf16 attention out

  dim3 blk(256);

  TRP tp{};
  tp.src[0] = Wq_w; tp.dst[0] = Wtq;
  tp.src[1] = Wk_w; tp.dst[1] = Wtk;
  tp.src[2] = Wv_w; tp.dst[2] = Wtv;
  tp.src[3] = Wr_w; tp.dst[3] = Wtr;
  tp.src[4] = Wo_w; tp.dst[4] = Wto;
  tr_cvt_all<<<dim3(1280), blk, 0, stream>>>(tp);

  QPAll q{};
  q.qin = inputs_q; q.kvin = inputs_kv; q.pos = pos_embed;
  q.Wtq = Wtq; q.Wtk = Wtk; q.Wtv = Wtv; q.Wtr = Wtr;
  q.bq = Wq_b; q.bk = Wk_b; q.bv = Wv_b; q.rrb = rrb;
  q.qb = qb; q.qrr = qrr; q.kb = kb; q.rb = rb; q.vt = vt;
  qkvr_k<<<dim3(896), blk, 0, stream>>>(q);

  cb_k<<<dim3(256), blk, 0, stream>>>(kb, rwb, cb);

  fused_k<<<dim3(2048), dim3(256), FUSED_SMEM, stream>>>(qb, qrr, kb, vt, rb, cb, attnb);

  // Output projection: d_out = attn(bf16) @ Wo + bo
  GP o{};
  o.A = attnb; o.B = Wto; o.lda = 1024; o.ldb = 1024; o.K = 1024;
  o.bias = Wo_b; o.outF = (float*)d_out;
  gemm_o<<<dim3(8, 32), blk, 0, stream>>>(o);
}